// Round 3
// baseline (629.044 us; speedup 1.0000x reference)
//
#include <hip/hip_runtime.h>
#include <cstdint>

// DynamicExpert: act = topk60(sigmoid(act @ synapse.T)), 2 steps.
// B=8, DIM=8192, fp32. Memory-bound: 256 MB of W streamed per step.
// R3: W-stationary K-split gemm. Block = 32 W-rows x 1024 K-slice; stages
// A[8][1024] (32 KB) in LDS once, streams its W chunk exactly once (8 HBM
// dwordx4 in flight per wave-window), writes 64 partials/wave to P.
// Final K-combine + sigmoid is fused into the topk kernel.

#define DIM 8192
#define BATCH 8
#define KPARTS 8
#define KRANGE (DIM / KPARTS)     // 1024
#define ROWS_PB 32                // W rows per block
#define WIN 256                   // j per inner window (64 lanes x float4)

// P layout: P[(b*KPARTS + p)*DIM + row]  -> 8*8*8192 floats = 2 MB
// grid: (DIM/ROWS_PB) * KPARTS = 256*8 = 2048 blocks, 256 threads.
__global__ __launch_bounds__(256) void gemv_part(
    const float* __restrict__ A,   // [8][DIM]
    const float* __restrict__ W,   // [DIM][DIM]
    float* __restrict__ P)
{
    __shared__ float As[BATCH][KRANGE];   // 32 KB

    const int tid  = threadIdx.x;
    const int lane = tid & 63;
    const int wid  = tid >> 6;
    const int p     = blockIdx.x & (KPARTS - 1);
    const int chunk = blockIdx.x >> 3;            // 0..255
    const int jbeg  = p * KRANGE;

    // stage A slice: thread t copies A[b][jbeg + 4t .. +3] for all 8 b
    {
        const int j = tid * 4;                    // 0..1020
#pragma unroll
        for (int b = 0; b < BATCH; ++b)
            *(float4*)(&As[b][j]) = *(const float4*)(A + b * DIM + jbeg + j);
    }
    __syncthreads();

    const int wrow0 = chunk * ROWS_PB + wid * 8;  // wave's 8 W rows

    float acc[8][BATCH];
#pragma unroll
    for (int r = 0; r < 8; ++r)
#pragma unroll
        for (int b = 0; b < BATCH; ++b) acc[r][b] = 0.0f;

    for (int w = 0; w < KRANGE; w += WIN) {
        const int j = w + lane * 4;
        float4 wv[8];
#pragma unroll
        for (int r = 0; r < 8; ++r)
            wv[r] = *(const float4*)(W + (size_t)(wrow0 + r) * DIM + jbeg + j);
        float4 a[8];
#pragma unroll
        for (int b = 0; b < BATCH; ++b)
            a[b] = *(const float4*)(&As[b][j]);
#pragma unroll
        for (int r = 0; r < 8; ++r) {
#pragma unroll
            for (int b = 0; b < BATCH; ++b) {
                acc[r][b] += wv[r].x * a[b].x;
                acc[r][b] += wv[r].y * a[b].y;
                acc[r][b] += wv[r].z * a[b].z;
                acc[r][b] += wv[r].w * a[b].w;
            }
        }
    }

    // reduce each of the 64 sums across the wave; lane 0 stores partial
#pragma unroll
    for (int r = 0; r < 8; ++r) {
#pragma unroll
        for (int b = 0; b < BATCH; ++b) {
            float v = acc[r][b];
#pragma unroll
            for (int off = 32; off > 0; off >>= 1)
                v += __shfl_down(v, off, 64);
            if (lane == 0)
                P[(size_t)(b * KPARTS + p) * DIM + wrow0 + r] = v;
        }
    }
}

// Per batch-row block: combine KPARTS partials, sigmoid, then top-k
// sparsify. Sigmoid outputs in (0,1): uint bit order == float order.
// Binary search on bit patterns, one __syncthreads per iteration
// (double-buffered partial counts); ties claimed via shared atomic.
__global__ __launch_bounds__(256) void topk_combine(
    const float* __restrict__ P,
    float* __restrict__ Yout,
    const int* __restrict__ kptr)
{
    const int row  = blockIdx.x;     // batch index b
    const int tid  = threadIdx.x;
    const int lane = tid & 63;
    const int wid  = tid >> 6;
    int k = kptr ? *kptr : 60;
    if (k > DIM) k = DIM;

    uint32_t v[32];
    const float* src = P + (size_t)row * KPARTS * DIM;
#pragma unroll
    for (int i = 0; i < 32; ++i) {
        const int idx = tid + i * 256;
        float x = 0.0f;
#pragma unroll
        for (int pp = 0; pp < KPARTS; ++pp)
            x += src[pp * DIM + idx];
        v[i] = __float_as_uint(1.0f / (1.0f + __expf(-x)));
    }

    __shared__ int s_part[2][4];
    __shared__ int s_ctr;
    int pb = 0;

    uint32_t lo = 0u, hi = 0x3F800000u;   // (0,1): f(1.0)=0 < k
    while (hi - lo > 1u) {
        const uint32_t mid = lo + ((hi - lo) >> 1);
        int c = 0;
#pragma unroll
        for (int i = 0; i < 32; ++i) c += (v[i] >= mid) ? 1 : 0;
#pragma unroll
        for (int off = 32; off > 0; off >>= 1)
            c += __shfl_down(c, off, 64);
        if (lane == 0) s_part[pb][wid] = c;
        __syncthreads();
        const int tot = s_part[pb][0] + s_part[pb][1]
                      + s_part[pb][2] + s_part[pb][3];
        pb ^= 1;
        if (tot >= k) lo = mid; else hi = mid;
    }
    const uint32_t cutoff = lo;   // k-th largest value's bits

    // strictly-greater count sizes the tie quota
    int needg;
    {
        int c = 0;
#pragma unroll
        for (int i = 0; i < 32; ++i) c += (v[i] > cutoff) ? 1 : 0;
#pragma unroll
        for (int off = 32; off > 0; off >>= 1)
            c += __shfl_down(c, off, 64);
        if (lane == 0) s_part[pb][wid] = c;
        if (tid == 0) s_ctr = 0;
        __syncthreads();
        needg = s_part[pb][0] + s_part[pb][1]
              + s_part[pb][2] + s_part[pb][3];
    }
    const int need_eq = k - needg;

    float* dst = Yout + (size_t)row * DIM;
#pragma unroll
    for (int i = 0; i < 32; ++i) {
        const uint32_t b = v[i];
        float val = 0.0f;
        if (b > cutoff) {
            val = __uint_as_float(b);
        } else if (b == cutoff) {
            const int pos = atomicAdd(&s_ctr, 1);
            if (pos < need_eq) val = __uint_as_float(b);
        }
        dst[tid + i * 256] = val;
    }
}

extern "C" void kernel_launch(void* const* d_in, const int* in_sizes, int n_in,
                              void* d_out, int out_size, void* d_ws, size_t ws_size,
                              hipStream_t stream) {
    const float* sdr = (const float*)d_in[0];
    const float* syn = (const float*)d_in[1];
    const int* kptr  = (n_in > 3) ? (const int*)d_in[3] : nullptr;
    float* out = (float*)d_out;
    float* P   = (float*)d_ws;            // 2 MB of partials

    // step 1
    gemv_part<<<(DIM / ROWS_PB) * KPARTS, 256, 0, stream>>>(sdr, syn, P);
    topk_combine<<<BATCH, 256, 0, stream>>>(P, out, kptr);
    // step 2 (input = step-1 sparse activations, dense layout)
    gemv_part<<<(DIM / ROWS_PB) * KPARTS, 256, 0, stream>>>(out, syn, P);
    topk_combine<<<BATCH, 256, 0, stream>>>(P, out, kptr);
}

// Round 4
// 485.095 us; speedup vs baseline: 1.2967x; 1.2967x over previous
//
#include <hip/hip_runtime.h>
#include <cstdint>

// DynamicExpert: act = topk60(sigmoid(act @ synapse.T)), 2 steps.
// B=8, DIM=8192, fp32. Memory-bound on streaming W (256 MB/step).
// R4: occupancy-first gemv. Evidence: BW scales with waves/SIMD
// (2/SIMD -> 1.25 TB/s, 4/SIMD -> 2.1 TB/s). Target 8 waves/SIMD:
// <=64 VGPR (launch_bounds(256,8)) and 2048 blocks (8 blocks/CU).
// Wave = 2 W rows x half-K; the two K-halves of a row-pair live in
// adjacent waves of one block; LDS combine + sigmoid in the tail.

#define DIM 8192
#define BATCH 8

__device__ __forceinline__ float sigmoidf_(float x) {
    return 1.0f / (1.0f + __expf(-x));
}

// grid: 2048 blocks x 256 thr. Block beta owns row-pairs {2b, 2b+1}.
// wave w (0..3): rowpair rp = 2*beta + (w>>1), khalf = w&1.
// Per 256-j window a lane does 2 HBM float4 (W rows) + 8 L2 float4 (A)
// + 64 FMAs. acc: 16 regs -> total ~55 VGPR -> 8 waves/SIMD.
__global__ __launch_bounds__(256, 8) void gemv8_sigmoid(
    const float* __restrict__ A,
    const float* __restrict__ W,
    float* __restrict__ Y)
{
    const int lane = threadIdx.x & 63;
    const int wid  = threadIdx.x >> 6;
    const int rp   = blockIdx.x * 2 + (wid >> 1);
    const int kh   = wid & 1;
    const int i0   = rp * 2;
    const int jbeg = kh * (DIM / 2);

    float acc0[BATCH], acc1[BATCH];
#pragma unroll
    for (int b = 0; b < BATCH; ++b) { acc0[b] = 0.0f; acc1[b] = 0.0f; }

    const float* wp0 = W + (size_t)i0 * DIM + jbeg + lane * 4;
    const float* wp1 = wp0 + DIM;
    const float* ap  = A + jbeg + lane * 4;

#pragma unroll 1
    for (int w = 0; w < DIM / 2; w += 256) {
        const float4 w0 = *(const float4*)wp0;
        const float4 w1 = *(const float4*)wp1;
#pragma unroll
        for (int b = 0; b < BATCH; ++b) {
            const float4 a = *(const float4*)(ap + b * DIM);
            acc0[b] += w0.x * a.x + w0.y * a.y + w0.z * a.z + w0.w * a.w;
            acc1[b] += w1.x * a.x + w1.y * a.y + w1.z * a.z + w1.w * a.w;
        }
        wp0 += 256; wp1 += 256; ap += 256;
    }

    // reduce 16 sums across the wave; lane 0 -> LDS partials
    __shared__ float part[2][2][2][BATCH];   // [rp_in_blk][khalf][row][b]
#pragma unroll
    for (int b = 0; b < BATCH; ++b) {
        float v0 = acc0[b], v1 = acc1[b];
#pragma unroll
        for (int off = 32; off > 0; off >>= 1) {
            v0 += __shfl_down(v0, off, 64);
            v1 += __shfl_down(v1, off, 64);
        }
        if (lane == 0) {
            part[wid >> 1][kh][0][b] = v0;
            part[wid >> 1][kh][1][b] = v1;
        }
    }
    __syncthreads();

    // combine K-halves, sigmoid, store: 32 outputs (2 rp x 2 rows x 8 b)
    if (threadIdx.x < 32) {
        const int b  = threadIdx.x & 7;
        const int r  = (threadIdx.x >> 3) & 1;
        const int q  = threadIdx.x >> 4;
        const float s = part[q][0][r][b] + part[q][1][r][b];
        const int row = (blockIdx.x * 2 + q) * 2 + r;
        Y[b * DIM + row] = sigmoidf_(s);
    }
}

// Per row (block): keep top-k values, zero the rest. Sigmoid outputs in
// (0,1): uint bit order == float order. Row in 32 regs/thread; binary
// search on bit patterns, one __syncthreads per iter (double-buffered
// counts); ties claimed via shared atomic. In-place safe: all loads
// complete before the first __syncthreads().
__global__ __launch_bounds__(256) void topk_sparsify(
    const float* __restrict__ Yin,
    float* __restrict__ Yout,
    const int* __restrict__ kptr)
{
    const int row  = blockIdx.x;
    const int tid  = threadIdx.x;
    const int lane = tid & 63;
    const int wid  = tid >> 6;
    int k = kptr ? *kptr : 60;
    if (k > DIM) k = DIM;

    uint32_t v[32];
    const float* src = Yin + (size_t)row * DIM;
#pragma unroll
    for (int i = 0; i < 32; ++i)
        v[i] = __float_as_uint(src[tid + i * 256]);

    __shared__ int s_part[2][4];
    __shared__ int s_ctr;
    int pb = 0;

    uint32_t lo = 0u, hi = 0x3F800000u;   // (0,1): count(v>=1.0f)=0 < k
    while (hi - lo > 1u) {
        const uint32_t mid = lo + ((hi - lo) >> 1);
        int c = 0;
#pragma unroll
        for (int i = 0; i < 32; ++i) c += (v[i] >= mid) ? 1 : 0;
#pragma unroll
        for (int off = 32; off > 0; off >>= 1)
            c += __shfl_down(c, off, 64);
        if (lane == 0) s_part[pb][wid] = c;
        __syncthreads();
        const int tot = s_part[pb][0] + s_part[pb][1]
                      + s_part[pb][2] + s_part[pb][3];
        pb ^= 1;
        if (tot >= k) lo = mid; else hi = mid;
    }
    const uint32_t cutoff = lo;

    int needg;
    {
        int c = 0;
#pragma unroll
        for (int i = 0; i < 32; ++i) c += (v[i] > cutoff) ? 1 : 0;
#pragma unroll
        for (int off = 32; off > 0; off >>= 1)
            c += __shfl_down(c, off, 64);
        if (lane == 0) s_part[pb][wid] = c;
        if (tid == 0) s_ctr = 0;
        __syncthreads();
        needg = s_part[pb][0] + s_part[pb][1]
              + s_part[pb][2] + s_part[pb][3];
    }
    const int need_eq = k - needg;

    float* dst = Yout + (size_t)row * DIM;
#pragma unroll
    for (int i = 0; i < 32; ++i) {
        const uint32_t b = v[i];
        float val = 0.0f;
        if (b > cutoff) {
            val = __uint_as_float(b);
        } else if (b == cutoff) {
            const int pos = atomicAdd(&s_ctr, 1);
            if (pos < need_eq) val = __uint_as_float(b);
        }
        dst[tid + i * 256] = val;
    }
}

extern "C" void kernel_launch(void* const* d_in, const int* in_sizes, int n_in,
                              void* d_out, int out_size, void* d_ws, size_t ws_size,
                              hipStream_t stream) {
    const float* sdr = (const float*)d_in[0];
    const float* syn = (const float*)d_in[1];
    const int* kptr  = (n_in > 3) ? (const int*)d_in[3] : nullptr;
    float* out = (float*)d_out;
    float* tmp = (float*)d_ws;            // 256 KB scratch

    // step 1: y = sigmoid(sdr @ W^T) -> d_out, sparsify in place
    gemv8_sigmoid<<<2048, 256, 0, stream>>>(sdr, syn, out);
    topk_sparsify<<<8, 256, 0, stream>>>(out, out, kptr);
    // step 2: y = sigmoid(act1 @ W^T) -> ws, sparsify -> d_out
    gemv8_sigmoid<<<2048, 256, 0, stream>>>(out, syn, tmp);
    topk_sparsify<<<8, 256, 0, stream>>>(tmp, out, kptr);
}